// Round 6
// baseline (266.806 us; speedup 1.0000x reference)
//
#include <hip/hip_runtime.h>
#include <stdint.h>

// MultiHeadedAttention: B=2, D_MODEL=1024, N=2048, H=16, HD=64.
// fp32 I/O, bf16 internal. Round 6: attn split-K2 (additive max-free partials,
// fp32, no atomics) + combine kernel; proj_o retiled 64x128 (512 blocks);
// softmax scale folded into Q at the qkv epilogue.
#define DM 1024
#define NS 2048
#define NH 16
#define HD 64
#define SQ 72   // padded LDS row stride (u16) for 64-wide tiles

typedef unsigned short u16;
typedef __attribute__((ext_vector_type(8))) short short8;
typedef __attribute__((ext_vector_type(8))) unsigned short u16x8;
typedef __attribute__((ext_vector_type(4))) float f32x4;
typedef __attribute__((ext_vector_type(4))) unsigned short u16x4;

static __device__ __forceinline__ u16 f2bf(float f) {
  union { float f; uint32_t i; } x; x.f = f;
  return (u16)((x.i + 0x7fffu + ((x.i >> 16) & 1u)) >> 16);
}
// async global->LDS, 16B/lane; LDS side wave-uniform base + lane*16 at all sites.
static __device__ __forceinline__ void gload16(u16* lds, const u16* g) {
  auto l = (__attribute__((address_space(3))) uint32_t*)(uint32_t)(uintptr_t)lds;
  auto gp = (const __attribute__((address_space(1))) uint32_t*)(uintptr_t)g;
  __builtin_amdgcn_global_load_lds(gp, l, 16, 0, 0);
}

// -------- fused weight convert: 4x fp32[DM*DM] -> bf16 --------
__global__ __launch_bounds__(256) void cvt4_k(const float* __restrict__ a,
                                              const float* __restrict__ b,
                                              const float* __restrict__ c,
                                              const float* __restrict__ d,
                                              u16* __restrict__ oa, u16* __restrict__ ob,
                                              u16* __restrict__ oc, u16* __restrict__ od) {
  const int y = blockIdx.y;
  const float* in = y == 0 ? a : y == 1 ? b : y == 2 ? c : d;
  u16* out = y == 0 ? oa : y == 1 ? ob : y == 2 ? oc : od;
  int i = (blockIdx.x * 256 + threadIdx.x) * 4;
  f32x4 v = *(const f32x4*)(in + i);
  u16x4 o;
  o.x = f2bf(v.x); o.y = f2bf(v.y); o.z = f2bf(v.z); o.w = f2bf(v.w);
  *(u16x4*)(out + i) = o;
}

// -------- fused input transpose+downcast: fp32 [DM][NS] -> bf16 [NS][DM] -----
__global__ __launch_bounds__(256) void trf3_k(const float* __restrict__ q,
                                              const float* __restrict__ k,
                                              const float* __restrict__ v,
                                              u16* __restrict__ oq, u16* __restrict__ ok,
                                              u16* __restrict__ ov) {
  __shared__ __attribute__((aligned(16))) u16 t[64][65];
  const int z = blockIdx.z, b = z & 1, which = z >> 1;
  const float* in = which == 0 ? q : which == 1 ? k : v;
  u16* out = which == 0 ? oq : which == 1 ? ok : ov;
  const float* ip = in + (size_t)b * DM * NS;
  u16* op = out + (size_t)b * DM * NS;
  const int r0 = blockIdx.y * 64, c0 = blockIdx.x * 64;
  const int tx = threadIdx.x, ty = threadIdx.y;  // 16x16
#pragma unroll
  for (int j = 0; j < 4; ++j) {
    int row = ty + j * 16;
    f32x4 vv = *(const f32x4*)(ip + (size_t)(r0 + row) * NS + c0 + tx * 4);
    t[row][tx * 4 + 0] = f2bf(vv.x); t[row][tx * 4 + 1] = f2bf(vv.y);
    t[row][tx * 4 + 2] = f2bf(vv.z); t[row][tx * 4 + 3] = f2bf(vv.w);
  }
  __syncthreads();
#pragma unroll
  for (int j = 0; j < 4; ++j) {
    int crow = ty + j * 16;
    u16x4 vv;
    vv.x = t[tx * 4 + 0][crow]; vv.y = t[tx * 4 + 1][crow];
    vv.z = t[tx * 4 + 2][crow]; vv.w = t[tx * 4 + 3][crow];
    *(u16x4*)(op + (size_t)(c0 + crow) * DM + r0 + tx * 4) = vv;
  }
}

// -------- bf16 transpose [DM][NS] -> [NS][DM] per batch (for attn out) -------
__global__ __launch_bounds__(256) void tr_k(const u16* __restrict__ in,
                                            u16* __restrict__ out) {
  __shared__ __attribute__((aligned(16))) u16 t[64][65];
  const int b = blockIdx.z;
  const u16* ip = in + (size_t)b * DM * NS;
  u16* op = out + (size_t)b * DM * NS;
  const int r0 = blockIdx.y * 64, c0 = blockIdx.x * 64;
  const int tx = threadIdx.x, ty = threadIdx.y;
#pragma unroll
  for (int j = 0; j < 4; ++j) {
    int row = ty + j * 16;
    u16x4 v = *(const u16x4*)(ip + (size_t)(r0 + row) * NS + c0 + tx * 4);
    t[row][tx * 4 + 0] = v.x; t[row][tx * 4 + 1] = v.y;
    t[row][tx * 4 + 2] = v.z; t[row][tx * 4 + 3] = v.w;
  }
  __syncthreads();
#pragma unroll
  for (int j = 0; j < 4; ++j) {
    int crow = ty + j * 16;
    u16x4 v;
    v.x = t[tx * 4 + 0][crow]; v.y = t[tx * 4 + 1][crow];
    v.z = t[tx * 4 + 2][crow]; v.w = t[tx * 4 + 3][crow];
    *(u16x4*)(op + (size_t)(c0 + crow) * DM + r0 + tx * 4) = v;
  }
}

// ---------------- fused QKV projection GEMM ----------------
// grid (NS/128, DM/128, 6); z = which*2 + b.  128x128 tile, BK=32.
// Q output is pre-scaled by SC = 0.125*log2(e) (folded softmax scale).
__global__ __launch_bounds__(256) void qkv_k(
    const u16* __restrict__ Xq, const u16* __restrict__ Xk, const u16* __restrict__ Xv,
    const u16* __restrict__ Wq, const u16* __restrict__ Wk, const u16* __restrict__ Wv,
    const float* __restrict__ bq, const float* __restrict__ bk, const float* __restrict__ bv,
    u16* __restrict__ QH, u16* __restrict__ KH, u16* __restrict__ VH) {
  __shared__ __attribute__((aligned(16))) u16 As[128 * 32];
  __shared__ __attribute__((aligned(16))) u16 Bs[128 * 32];
  const int z = blockIdx.z, b = z & 1, which = z >> 1;
  const u16* X = which == 0 ? Xq : which == 1 ? Xk : Xv;
  const u16* W = which == 0 ? Wq : which == 1 ? Wk : Wv;
  const float* bias = which == 0 ? bq : which == 1 ? bk : bv;
  u16* out = which == 0 ? QH : which == 1 ? KH : VH;
  const float sc = which == 0 ? 0.18033688011112042f : 1.0f;  // 0.125*log2e
  const int m0 = blockIdx.x * 128;
  const int c0 = blockIdx.y * 128;
  const u16* Xb = X + (size_t)b * NS * DM;
  const int tid = threadIdx.x;
  const int lane = tid & 63, w = tid >> 6;
  const int wm = w >> 1, wc = w & 1;
  const int qd = lane >> 4, ml = lane & 15;

  f32x4 acc[4][4];
#pragma unroll
  for (int i = 0; i < 4; ++i)
#pragma unroll
    for (int j = 0; j < 4; ++j) acc[i][j] = (f32x4){0.f, 0.f, 0.f, 0.f};

  for (int k0 = 0; k0 < DM; k0 += 32) {
    __syncthreads();
#pragma unroll
    for (int it = 0; it < 2; ++it) {
      int ci = it * 256 + tid;
      int row = ci >> 2, j = ci & 3;
      gload16(&As[ci * 8], Xb + (size_t)(m0 + row) * DM + k0 + j * 8);
      gload16(&Bs[ci * 8], W + (size_t)(c0 + row) * DM + k0 + j * 8);
    }
    __syncthreads();
    short8 af[4], bf[4];
#pragma unroll
    for (int i = 0; i < 4; ++i) {
      af[i] = *(const short8*)&As[(wm * 64 + i * 16 + ml) * 32 + qd * 8];
      bf[i] = *(const short8*)&Bs[(wc * 64 + i * 16 + ml) * 32 + qd * 8];
    }
#pragma unroll
    for (int mi = 0; mi < 4; ++mi)
#pragma unroll
      for (int ci2 = 0; ci2 < 4; ++ci2)
        acc[mi][ci2] = __builtin_amdgcn_mfma_f32_16x16x32_bf16(af[mi], bf[ci2],
                                                               acc[mi][ci2], 0, 0, 0);
  }

  const int cw = c0 + wc * 64;
  const int mw = m0 + wm * 64;
  float bv4[4];
#pragma unroll
  for (int ci2 = 0; ci2 < 4; ++ci2) bv4[ci2] = bias[cw + ci2 * 16 + ml];

  if (which < 2) {
    const int h = ml, d0 = cw >> 4;
    u16* ob = out + ((size_t)(b * NH + h) * NS) * HD;
#pragma unroll
    for (int mi = 0; mi < 4; ++mi) {
#pragma unroll
      for (int r = 0; r < 4; ++r) {
        int n = mw + mi * 16 + qd * 4 + r;
        u16x4 v;
        v.x = f2bf((acc[mi][0][r] + bv4[0]) * sc);
        v.y = f2bf((acc[mi][1][r] + bv4[1]) * sc);
        v.z = f2bf((acc[mi][2][r] + bv4[2]) * sc);
        v.w = f2bf((acc[mi][3][r] + bv4[3]) * sc);
        *(u16x4*)(ob + (size_t)n * HD + d0) = v;
      }
    }
  } else {
#pragma unroll
    for (int ci2 = 0; ci2 < 4; ++ci2) {
      int c = cw + ci2 * 16 + ml;
      int h = c & 15, d = c >> 4;
#pragma unroll
      for (int mi = 0; mi < 4; ++mi) {
        int nb = mw + mi * 16 + qd * 4;
        u16x4 v;
        v.x = f2bf(acc[mi][ci2][0] + bv4[ci2]); v.y = f2bf(acc[mi][ci2][1] + bv4[ci2]);
        v.z = f2bf(acc[mi][ci2][2] + bv4[ci2]); v.w = f2bf(acc[mi][ci2][3] + bv4[ci2]);
        *(u16x4*)(out + ((size_t)(b * NH + h) * HD + d) * NS + nb) = v;
      }
    }
  }
}

// ---------------- output projection, 64x128 tiles (fp32 out) ----------------
__global__ __launch_bounds__(256) void proj_o(const u16* __restrict__ X,
                                              const u16* __restrict__ W,
                                              const float* __restrict__ bias,
                                              float* __restrict__ out) {
  __shared__ __attribute__((aligned(16))) u16 As[64 * 32];
  __shared__ __attribute__((aligned(16))) u16 Bs[128 * 32];
  const int b = blockIdx.z;
  const int m0 = blockIdx.x * 64;
  const int c0 = blockIdx.y * 128;
  const u16* Xb = X + (size_t)b * NS * DM;
  const int tid = threadIdx.x;
  const int lane = tid & 63, w = tid >> 6;
  const int wm = w >> 1, wc = w & 1;  // wave tile: 32 rows x 64 cols
  const int qd = lane >> 4, ml = lane & 15;

  f32x4 acc[2][4];
#pragma unroll
  for (int i = 0; i < 2; ++i)
#pragma unroll
    for (int j = 0; j < 4; ++j) acc[i][j] = (f32x4){0.f, 0.f, 0.f, 0.f};

  for (int k0 = 0; k0 < DM; k0 += 32) {
    __syncthreads();
    {  // A: 256 chunks (64 rows x 4), one per thread
      int row = tid >> 2, j = tid & 3;
      gload16(&As[tid * 8], Xb + (size_t)(m0 + row) * DM + k0 + j * 8);
    }
#pragma unroll
    for (int it = 0; it < 2; ++it) {  // B: 512 chunks (128 rows x 4)
      int ci = it * 256 + tid;
      int row = ci >> 2, j = ci & 3;
      gload16(&Bs[ci * 8], W + (size_t)(c0 + row) * DM + k0 + j * 8);
    }
    __syncthreads();
    short8 af[2], bf[4];
#pragma unroll
    for (int i = 0; i < 2; ++i)
      af[i] = *(const short8*)&As[(wm * 32 + i * 16 + ml) * 32 + qd * 8];
#pragma unroll
    for (int i = 0; i < 4; ++i)
      bf[i] = *(const short8*)&Bs[(wc * 64 + i * 16 + ml) * 32 + qd * 8];
#pragma unroll
    for (int mi = 0; mi < 2; ++mi)
#pragma unroll
      for (int ci2 = 0; ci2 < 4; ++ci2)
        acc[mi][ci2] = __builtin_amdgcn_mfma_f32_16x16x32_bf16(af[mi], bf[ci2],
                                                               acc[mi][ci2], 0, 0, 0);
  }

  const int cw = c0 + wc * 64;
  const int mw = m0 + wm * 32;
#pragma unroll
  for (int ci2 = 0; ci2 < 4; ++ci2) {
    int c = cw + ci2 * 16 + ml;
    float bv = bias[c];
#pragma unroll
    for (int mi = 0; mi < 2; ++mi) {
      int nb = mw + mi * 16 + qd * 4;
      f32x4 v;
      v.x = acc[mi][ci2][0] + bv; v.y = acc[mi][ci2][1] + bv;
      v.z = acc[mi][ci2][2] + bv; v.w = acc[mi][ci2][3] + bv;
      *(f32x4*)(out + ((size_t)b * DM + c) * NS + nb) = v;
    }
  }
}

// ---------------- flash attention, split-K2, fp32 additive partials ----------
// Q,K: [bh][n][d] (Q pre-scaled by 0.125*log2e), V: [bh][d][n].
// grid (NS/64, 32, 2): z = key-half. Each block: 64 q-rows x 1024 keys.
// Writes unnormalized O (fp32, [b][c][n]) and l (fp32, [half][bh][n]) once.
__global__ __launch_bounds__(256) void attn_k(const u16* __restrict__ Q,
                                              const u16* __restrict__ K,
                                              const u16* __restrict__ V,
                                              float* __restrict__ O0,
                                              float* __restrict__ O1,
                                              float* __restrict__ lp) {
  __shared__ __attribute__((aligned(16))) u16 QPs[64 * SQ];  // Q stage, then P
  __shared__ __attribute__((aligned(16))) u16 Ks[64 * SQ];
  __shared__ __attribute__((aligned(16))) u16 Vs[64 * SQ];
  const int bh = blockIdx.y, b = bh >> 4, h = bh & 15;
  const int half = blockIdx.z;
  const int n0 = blockIdx.x * 64;
  const u16* Qb = Q + (size_t)bh * NS * HD;
  const u16* Kb = K + (size_t)bh * NS * HD + (size_t)half * (NS / 2) * HD;
  const u16* Vb = V + (size_t)bh * HD * NS + (size_t)half * (NS / 2);
  const int tid = threadIdx.x, lane = tid & 63, w = tid >> 6;
  const int qd = lane >> 4, ml = lane & 15;

  // stage Q once (64 rows x 8 chunks of 8 u16)
#pragma unroll
  for (int it = 0; it < 2; ++it) {
    int ci = it * 256 + tid;
    int row = ci >> 3, j = ci & 7;
    *(u16x8*)&QPs[row * SQ + j * 8] = *(const u16x8*)(Qb + (size_t)(n0 + row) * HD + j * 8);
  }
  __syncthreads();
  short8 aq[2];
#pragma unroll
  for (int ks = 0; ks < 2; ++ks)
    aq[ks] = *(const short8*)&QPs[(w * 16 + ml) * SQ + (ks * 4 + qd) * 8];
  // aq in VGPRs; QPs reused for P after kb=0 staging barriers.

  f32x4 O[4];
#pragma unroll
  for (int i = 0; i < 4; ++i) O[i] = (f32x4){0.f, 0.f, 0.f, 0.f};
  float lsum[4] = {0.f, 0.f, 0.f, 0.f};

  const int srow = tid >> 3, sj = tid & 7;  // staging: 8 chunks per 64-elem row

  for (int kb = 0; kb < (NS / 2) / 64; ++kb) {
    u16x8 kv[2], vv[2];
#pragma unroll
    for (int it = 0; it < 2; ++it) {  // global loads first (overlap prev compute)
      kv[it] = *(const u16x8*)(Kb + (size_t)(kb * 64 + srow + it * 32) * HD + sj * 8);
      vv[it] = *(const u16x8*)(Vb + (size_t)(srow + it * 32) * NS + kb * 64 + sj * 8);
    }
    __syncthreads();  // prior tile's Ks/Vs/Ps reads done (kb=0: Q frag reads)
#pragma unroll
    for (int it = 0; it < 2; ++it) {
      *(u16x8*)&Ks[(srow + it * 32) * SQ + sj * 8] = kv[it];
      *(u16x8*)&Vs[(srow + it * 32) * SQ + sj * 8] = vv[it];
    }
    __syncthreads();

    // S = Q K^T  (Q pre-scaled -> S already in exp2 domain)
    f32x4 S[4];
#pragma unroll
    for (int f = 0; f < 4; ++f) S[f] = (f32x4){0.f, 0.f, 0.f, 0.f};
#pragma unroll
    for (int f = 0; f < 4; ++f)
#pragma unroll
      for (int ks = 0; ks < 2; ++ks) {
        short8 bk = *(const short8*)&Ks[(f * 16 + ml) * SQ + (ks * 4 + qd) * 8];
        S[f] = __builtin_amdgcn_mfma_f32_16x16x32_bf16(aq[ks], bk, S[f], 0, 0, 0);
      }

    // P = exp2(S); write to QPs (P tile), accumulate per-lane row sums
#pragma unroll
    for (int f = 0; f < 4; ++f)
#pragma unroll
      for (int r = 0; r < 4; ++r) {
        float p = __builtin_amdgcn_exp2f(S[f][r]);
        QPs[(w * 16 + qd * 4 + r) * SQ + f * 16 + ml] = f2bf(p);
        lsum[r] += p;
      }
    __syncthreads();  // P writes (cross-lane) -> b128 reads below

    // O += P V
#pragma unroll
    for (int kk = 0; kk < 2; ++kk) {
      short8 ap = *(const short8*)&QPs[(w * 16 + ml) * SQ + (kk * 4 + qd) * 8];
#pragma unroll
      for (int df = 0; df < 4; ++df) {
        short8 bvv = *(const short8*)&Vs[(df * 16 + ml) * SQ + (kk * 4 + qd) * 8];
        O[df] = __builtin_amdgcn_mfma_f32_16x16x32_bf16(ap, bvv, O[df], 0, 0, 0);
      }
    }
  }

  // reduce row sums across the quad's 16 lanes
#pragma unroll
  for (int off = 1; off < 16; off <<= 1)
#pragma unroll
    for (int r = 0; r < 4; ++r) lsum[r] += __shfl_xor(lsum[r], off);

  float* Op = half ? O1 : O0;
  const int nb = n0 + w * 16 + qd * 4;
  if (ml == 0) {  // one lane per quad writes l[half][bh][nb..nb+3]
    f32x4 lv = {lsum[0], lsum[1], lsum[2], lsum[3]};
    *(f32x4*)(lp + ((size_t)(half * 32 + bh)) * NS + nb) = lv;
  }
#pragma unroll
  for (int df = 0; df < 4; ++df) {
    int d = df * 16 + ml;
    int c = d * NH + h;  // reshape: c = d*H + h
    *(f32x4*)(Op + ((size_t)b * DM + c) * NS + nb) = O[df];
  }
}

// ---------------- combine: XO = (O0+O1)/(l0+l1), bf16 [b][c][n] --------------
__global__ __launch_bounds__(256) void comb_k(const float* __restrict__ O0,
                                              const float* __restrict__ O1,
                                              const float* __restrict__ lp,
                                              u16* __restrict__ XO) {
  const size_t t = (size_t)blockIdx.x * 256 + threadIdx.x;  // f32x4 index
  const int n4 = (int)(t & (NS / 4 - 1));
  const int c = (int)((t >> 9) & (DM - 1));   // NS/4 = 512 = 2^9
  const int b = (int)(t >> 19);               // 512*1024 = 2^19
  const int h = c & 15;
  f32x4 o0 = *(const f32x4*)(O0 + t * 4);
  f32x4 o1 = *(const f32x4*)(O1 + t * 4);
  f32x4 l0 = *(const f32x4*)(lp + ((size_t)(b * 16 + h)) * NS + n4 * 4);
  f32x4 l1 = *(const f32x4*)(lp + ((size_t)(32 + b * 16 + h)) * NS + n4 * 4);
  u16x4 v;
  v.x = f2bf((o0.x + o1.x) / (l0.x + l1.x));
  v.y = f2bf((o0.y + o1.y) / (l0.y + l1.y));
  v.z = f2bf((o0.z + o1.z) / (l0.z + l1.z));
  v.w = f2bf((o0.w + o1.w) / (l0.w + l1.w));
  *(u16x4*)(XO + t * 4) = v;
}

extern "C" void kernel_launch(void* const* d_in, const int* in_sizes, int n_in,
                              void* d_out, int out_size, void* d_ws, size_t ws_size,
                              hipStream_t stream) {
  const float* query = (const float*)d_in[0];
  const float* key = (const float*)d_in[1];
  const float* value = (const float*)d_in[2];
  const float* Wq = (const float*)d_in[3]; const float* bq = (const float*)d_in[4];
  const float* Wk = (const float*)d_in[5]; const float* bk = (const float*)d_in[6];
  const float* Wv = (const float*)d_in[7]; const float* bv = (const float*)d_in[8];
  const float* Wm = (const float*)d_in[9]; const float* bm = (const float*)d_in[10];

  u16* ws = (u16*)d_ws;
  const size_t TS = (size_t)2 * NS * DM;   // 4,194,304 u16 elems
  const size_t WSZ = (size_t)DM * DM;
  // phase-1 regions
  u16* XTq = ws;               // dead after qkv_k
  u16* XTk = ws + TS;          // dead after qkv_k
  u16* XTv = ws + 2 * TS;      // dead after qkv_k
  u16* QH = ws + 3 * TS;       // dead after attn_k
  u16* KH = ws + 4 * TS;
  u16* VH = ws + 5 * TS;
  u16* Wqb = ws + 6 * TS;
  u16* Wkb = Wqb + WSZ;
  u16* Wvb = Wkb + WSZ;
  u16* Wmb = Wvb + WSZ;
  // phase-2 overlays: O0 (16.78 MB fp32) exactly covers XTq+XTk
  float* O0 = (float*)ws;
  float* O1 = (float*)(ws + 6 * TS + 4 * WSZ);          // fresh, +16.78 MB
  float* lp = O1 + (size_t)2 * DM * NS;                 // +0.5 MB
  u16* XO = XTv;   // bf16 [b][c][n], written by comb_k
  u16* XOT = QH;   // [n][c], written by tr_k after attn

  cvt4_k<<<dim3(WSZ / 1024, 4), 256, 0, stream>>>(Wq, Wk, Wv, Wm, Wqb, Wkb, Wvb, Wmb);

  dim3 tb(16, 16);
  trf3_k<<<dim3(NS / 64, DM / 64, 6), tb, 0, stream>>>(query, key, value, XTq, XTk, XTv);

  qkv_k<<<dim3(NS / 128, DM / 128, 6), 256, 0, stream>>>(
      XTq, XTk, XTv, Wqb, Wkb, Wvb, bq, bk, bv, QH, KH, VH);

  attn_k<<<dim3(NS / 64, 32, 2), 256, 0, stream>>>(QH, KH, VH, O0, O1, lp);

  comb_k<<<dim3((DM * NS * 2 / 4) / 256), 256, 0, stream>>>(O0, O1, lp, XO);

  tr_k<<<dim3(NS / 64, DM / 64, 2), tb, 0, stream>>>(XO, XOT);
  proj_o<<<dim3(NS / 64, DM / 128, 2), 256, 0, stream>>>(XOT, Wmb, bm, (float*)d_out);
}

// Round 9
// 263.497 us; speedup vs baseline: 1.0126x; 1.0126x over previous
//
#include <hip/hip_runtime.h>
#include <stdint.h>

// MultiHeadedAttention: B=2, D_MODEL=1024, N=2048, H=16, HD=64.
// fp32 I/O, bf16 internal. Round 9 = round 7/8 with the MFMA_PV macro defined
// directly (no __has_builtin: it returns false on the HOST pass for aux-target
// builtins and fired #error; round-7's device-pass diagnostics proved
// __builtin_amdgcn_mfma_f32_16x16x16bf16_1k resolves on gfx950).
// attn: S^T trick + PV via 16x16x16 MFMA keeps P in registers (no Ps LDS, no
// P barrier); K/V async double-buffered via global_load_lds (1 barrier/tile).
#define DM 1024
#define NS 2048
#define NH 16
#define HD 64

typedef unsigned short u16;
typedef __attribute__((ext_vector_type(8))) short short8;
typedef __attribute__((ext_vector_type(4))) short s16x4;
typedef __attribute__((ext_vector_type(8))) unsigned short u16x8;
typedef __attribute__((ext_vector_type(4))) float f32x4;
typedef __attribute__((ext_vector_type(4))) unsigned short u16x4;

// gfx90a+ legacy-shape MFMA, still present on gfx950 (ISA §10: v_mfma_f32_16x16x16_bf16)
#define MFMA_PV(a, b, c) __builtin_amdgcn_mfma_f32_16x16x16bf16_1k(a, b, c, 0, 0, 0)

static __device__ __forceinline__ u16 f2bf(float f) {
  union { float f; uint32_t i; } x; x.f = f;
  return (u16)((x.i + 0x7fffu + ((x.i >> 16) & 1u)) >> 16);
}
// async global->LDS, 16B/lane; LDS side wave-uniform base + lane*16 at all sites.
static __device__ __forceinline__ void gload16(u16* lds, const u16* g) {
  auto l = (__attribute__((address_space(3))) uint32_t*)(uint32_t)(uintptr_t)lds;
  auto gp = (const __attribute__((address_space(1))) uint32_t*)(uintptr_t)g;
  __builtin_amdgcn_global_load_lds(gp, l, 16, 0, 0);
}

// -------- fused weight convert: 4x fp32[DM*DM] -> bf16 --------
__global__ __launch_bounds__(256) void cvt4_k(const float* __restrict__ a,
                                              const float* __restrict__ b,
                                              const float* __restrict__ c,
                                              const float* __restrict__ d,
                                              u16* __restrict__ oa, u16* __restrict__ ob,
                                              u16* __restrict__ oc, u16* __restrict__ od) {
  const int y = blockIdx.y;
  const float* in = y == 0 ? a : y == 1 ? b : y == 2 ? c : d;
  u16* out = y == 0 ? oa : y == 1 ? ob : y == 2 ? oc : od;
  int i = (blockIdx.x * 256 + threadIdx.x) * 4;
  f32x4 v = *(const f32x4*)(in + i);
  u16x4 o;
  o.x = f2bf(v.x); o.y = f2bf(v.y); o.z = f2bf(v.z); o.w = f2bf(v.w);
  *(u16x4*)(out + i) = o;
}

// -------- fused input transpose+downcast: fp32 [DM][NS] -> bf16 [NS][DM] -----
__global__ __launch_bounds__(256) void trf3_k(const float* __restrict__ q,
                                              const float* __restrict__ k,
                                              const float* __restrict__ v,
                                              u16* __restrict__ oq, u16* __restrict__ ok,
                                              u16* __restrict__ ov) {
  __shared__ __attribute__((aligned(16))) u16 t[64][65];
  const int z = blockIdx.z, b = z & 1, which = z >> 1;
  const float* in = which == 0 ? q : which == 1 ? k : v;
  u16* out = which == 0 ? oq : which == 1 ? ok : ov;
  const float* ip = in + (size_t)b * DM * NS;
  u16* op = out + (size_t)b * DM * NS;
  const int r0 = blockIdx.y * 64, c0 = blockIdx.x * 64;
  const int tx = threadIdx.x, ty = threadIdx.y;  // 16x16
#pragma unroll
  for (int j = 0; j < 4; ++j) {
    int row = ty + j * 16;
    f32x4 vv = *(const f32x4*)(ip + (size_t)(r0 + row) * NS + c0 + tx * 4);
    t[row][tx * 4 + 0] = f2bf(vv.x); t[row][tx * 4 + 1] = f2bf(vv.y);
    t[row][tx * 4 + 2] = f2bf(vv.z); t[row][tx * 4 + 3] = f2bf(vv.w);
  }
  __syncthreads();
#pragma unroll
  for (int j = 0; j < 4; ++j) {
    int crow = ty + j * 16;
    u16x4 vv;
    vv.x = t[tx * 4 + 0][crow]; vv.y = t[tx * 4 + 1][crow];
    vv.z = t[tx * 4 + 2][crow]; vv.w = t[tx * 4 + 3][crow];
    *(u16x4*)(op + (size_t)(c0 + crow) * DM + r0 + tx * 4) = vv;
  }
}

// -------- bf16 transpose [DM][NS] -> [NS][DM] per batch (for attn out) -------
__global__ __launch_bounds__(256) void tr_k(const u16* __restrict__ in,
                                            u16* __restrict__ out) {
  __shared__ __attribute__((aligned(16))) u16 t[64][65];
  const int b = blockIdx.z;
  const u16* ip = in + (size_t)b * DM * NS;
  u16* op = out + (size_t)b * DM * NS;
  const int r0 = blockIdx.y * 64, c0 = blockIdx.x * 64;
  const int tx = threadIdx.x, ty = threadIdx.y;
#pragma unroll
  for (int j = 0; j < 4; ++j) {
    int row = ty + j * 16;
    u16x4 v = *(const u16x4*)(ip + (size_t)(r0 + row) * NS + c0 + tx * 4);
    t[row][tx * 4 + 0] = v.x; t[row][tx * 4 + 1] = v.y;
    t[row][tx * 4 + 2] = v.z; t[row][tx * 4 + 3] = v.w;
  }
  __syncthreads();
#pragma unroll
  for (int j = 0; j < 4; ++j) {
    int crow = ty + j * 16;
    u16x4 v;
    v.x = t[tx * 4 + 0][crow]; v.y = t[tx * 4 + 1][crow];
    v.z = t[tx * 4 + 2][crow]; v.w = t[tx * 4 + 3][crow];
    *(u16x4*)(op + (size_t)(c0 + crow) * DM + r0 + tx * 4) = v;
  }
}

// ---------------- fused QKV projection GEMM ----------------
// grid (NS/128, DM/128, 6); z = which*2 + b.  128x128 tile, BK=32.
// Q output is pre-scaled by SC = 0.125*log2(e) (folded softmax scale).
__global__ __launch_bounds__(256) void qkv_k(
    const u16* __restrict__ Xq, const u16* __restrict__ Xk, const u16* __restrict__ Xv,
    const u16* __restrict__ Wq, const u16* __restrict__ Wk, const u16* __restrict__ Wv,
    const float* __restrict__ bq, const float* __restrict__ bk, const float* __restrict__ bv,
    u16* __restrict__ QH, u16* __restrict__ KH, u16* __restrict__ VH) {
  __shared__ __attribute__((aligned(16))) u16 As[128 * 32];
  __shared__ __attribute__((aligned(16))) u16 Bs[128 * 32];
  const int z = blockIdx.z, b = z & 1, which = z >> 1;
  const u16* X = which == 0 ? Xq : which == 1 ? Xk : Xv;
  const u16* W = which == 0 ? Wq : which == 1 ? Wk : Wv;
  const float* bias = which == 0 ? bq : which == 1 ? bk : bv;
  u16* out = which == 0 ? QH : which == 1 ? KH : VH;
  const float sc = which == 0 ? 0.18033688011112042f : 1.0f;  // 0.125*log2e
  const int m0 = blockIdx.x * 128;
  const int c0 = blockIdx.y * 128;
  const u16* Xb = X + (size_t)b * NS * DM;
  const int tid = threadIdx.x;
  const int lane = tid & 63, w = tid >> 6;
  const int wm = w >> 1, wc = w & 1;
  const int qd = lane >> 4, ml = lane & 15;

  f32x4 acc[4][4];
#pragma unroll
  for (int i = 0; i < 4; ++i)
#pragma unroll
    for (int j = 0; j < 4; ++j) acc[i][j] = (f32x4){0.f, 0.f, 0.f, 0.f};

  for (int k0 = 0; k0 < DM; k0 += 32) {
    __syncthreads();
#pragma unroll
    for (int it = 0; it < 2; ++it) {
      int ci = it * 256 + tid;
      int row = ci >> 2, j = ci & 3;
      gload16(&As[ci * 8], Xb + (size_t)(m0 + row) * DM + k0 + j * 8);
      gload16(&Bs[ci * 8], W + (size_t)(c0 + row) * DM + k0 + j * 8);
    }
    __syncthreads();
    short8 af[4], bf[4];
#pragma unroll
    for (int i = 0; i < 4; ++i) {
      af[i] = *(const short8*)&As[(wm * 64 + i * 16 + ml) * 32 + qd * 8];
      bf[i] = *(const short8*)&Bs[(wc * 64 + i * 16 + ml) * 32 + qd * 8];
    }
#pragma unroll
    for (int mi = 0; mi < 4; ++mi)
#pragma unroll
      for (int ci2 = 0; ci2 < 4; ++ci2)
        acc[mi][ci2] = __builtin_amdgcn_mfma_f32_16x16x32_bf16(af[mi], bf[ci2],
                                                               acc[mi][ci2], 0, 0, 0);
  }

  const int cw = c0 + wc * 64;
  const int mw = m0 + wm * 64;
  float bv4[4];
#pragma unroll
  for (int ci2 = 0; ci2 < 4; ++ci2) bv4[ci2] = bias[cw + ci2 * 16 + ml];

  if (which < 2) {
    const int h = ml, d0 = cw >> 4;
    u16* ob = out + ((size_t)(b * NH + h) * NS) * HD;
#pragma unroll
    for (int mi = 0; mi < 4; ++mi) {
#pragma unroll
      for (int r = 0; r < 4; ++r) {
        int n = mw + mi * 16 + qd * 4 + r;
        u16x4 v;
        v.x = f2bf((acc[mi][0][r] + bv4[0]) * sc);
        v.y = f2bf((acc[mi][1][r] + bv4[1]) * sc);
        v.z = f2bf((acc[mi][2][r] + bv4[2]) * sc);
        v.w = f2bf((acc[mi][3][r] + bv4[3]) * sc);
        *(u16x4*)(ob + (size_t)n * HD + d0) = v;
      }
    }
  } else {
#pragma unroll
    for (int ci2 = 0; ci2 < 4; ++ci2) {
      int c = cw + ci2 * 16 + ml;
      int h = c & 15, d = c >> 4;
#pragma unroll
      for (int mi = 0; mi < 4; ++mi) {
        int nb = mw + mi * 16 + qd * 4;
        u16x4 v;
        v.x = f2bf(acc[mi][ci2][0] + bv4[ci2]); v.y = f2bf(acc[mi][ci2][1] + bv4[ci2]);
        v.z = f2bf(acc[mi][ci2][2] + bv4[ci2]); v.w = f2bf(acc[mi][ci2][3] + bv4[ci2]);
        *(u16x4*)(out + ((size_t)(b * NH + h) * HD + d) * NS + nb) = v;
      }
    }
  }
}

// ---------------- output projection, 64x128 tiles (fp32 out) ----------------
__global__ __launch_bounds__(256) void proj_o(const u16* __restrict__ X,
                                              const u16* __restrict__ W,
                                              const float* __restrict__ bias,
                                              float* __restrict__ out) {
  __shared__ __attribute__((aligned(16))) u16 As[64 * 32];
  __shared__ __attribute__((aligned(16))) u16 Bs[128 * 32];
  const int b = blockIdx.z;
  const int m0 = blockIdx.x * 64;
  const int c0 = blockIdx.y * 128;
  const u16* Xb = X + (size_t)b * NS * DM;
  const int tid = threadIdx.x;
  const int lane = tid & 63, w = tid >> 6;
  const int wm = w >> 1, wc = w & 1;  // wave tile: 32 rows x 64 cols
  const int qd = lane >> 4, ml = lane & 15;

  f32x4 acc[2][4];
#pragma unroll
  for (int i = 0; i < 2; ++i)
#pragma unroll
    for (int j = 0; j < 4; ++j) acc[i][j] = (f32x4){0.f, 0.f, 0.f, 0.f};

  for (int k0 = 0; k0 < DM; k0 += 32) {
    __syncthreads();
    {  // A: 256 chunks (64 rows x 4), one per thread
      int row = tid >> 2, j = tid & 3;
      gload16(&As[tid * 8], Xb + (size_t)(m0 + row) * DM + k0 + j * 8);
    }
#pragma unroll
    for (int it = 0; it < 2; ++it) {  // B: 512 chunks (128 rows x 4)
      int ci = it * 256 + tid;
      int row = ci >> 2, j = ci & 3;
      gload16(&Bs[ci * 8], W + (size_t)(c0 + row) * DM + k0 + j * 8);
    }
    __syncthreads();
    short8 af[2], bf[4];
#pragma unroll
    for (int i = 0; i < 2; ++i)
      af[i] = *(const short8*)&As[(wm * 32 + i * 16 + ml) * 32 + qd * 8];
#pragma unroll
    for (int i = 0; i < 4; ++i)
      bf[i] = *(const short8*)&Bs[(wc * 64 + i * 16 + ml) * 32 + qd * 8];
#pragma unroll
    for (int mi = 0; mi < 2; ++mi)
#pragma unroll
      for (int ci2 = 0; ci2 < 4; ++ci2)
        acc[mi][ci2] = __builtin_amdgcn_mfma_f32_16x16x32_bf16(af[mi], bf[ci2],
                                                               acc[mi][ci2], 0, 0, 0);
  }

  const int cw = c0 + wc * 64;
  const int mw = m0 + wm * 32;
#pragma unroll
  for (int ci2 = 0; ci2 < 4; ++ci2) {
    int c = cw + ci2 * 16 + ml;
    float bv = bias[c];
#pragma unroll
    for (int mi = 0; mi < 2; ++mi) {
      int nb = mw + mi * 16 + qd * 4;
      f32x4 v;
      v.x = acc[mi][ci2][0] + bv; v.y = acc[mi][ci2][1] + bv;
      v.z = acc[mi][ci2][2] + bv; v.w = acc[mi][ci2][3] + bv;
      *(f32x4*)(out + ((size_t)b * DM + c) * NS + nb) = v;
    }
  }
}

// ---------------- flash attention, register-P, async dbuf ----------------
// Q,K: [bh][n][d] (Q pre-scaled by 0.125*log2e), V: [bh][d][n].
// grid (NS/64, 32). Per block: 64 q-rows x all 2048 keys, 32 tiles of 64 keys.
// S^T = mfma(K_frag, Q_frag): C-layout col=qrow(lane&15), row=key(quad*4+r) ==
// exactly the 16x16x16 A-operand layout -> P stays in VGPRs (exp2+pack only).
// K/V double-buffered in LDS via global_load_lds; ONE barrier per tile.
// LDS slabs of [64 rows][32 u16]: K frag b128 = m97 bank pattern; V key-chunks
// xor-swizzled by (d&3) so b64 frag reads spread over 16 start-banks.
__global__ __launch_bounds__(256) void attn_k(const u16* __restrict__ Q,
                                              const u16* __restrict__ K,
                                              const u16* __restrict__ V,
                                              u16* __restrict__ XO) {
  __shared__ __attribute__((aligned(16))) u16 Ks[2 * 2 * 2048];  // [buf][slab][64][32]
  __shared__ __attribute__((aligned(16))) u16 Vs[2 * 2 * 2048];  // [buf][slab][64 d][32]
  const int bh = blockIdx.y, b = bh >> 4, h = bh & 15;
  const int n0 = blockIdx.x * 64;
  const u16* Qb = Q + (size_t)bh * NS * HD;
  const u16* Kb = K + (size_t)bh * NS * HD;
  const u16* Vb = V + (size_t)bh * HD * NS;
  const int tid = threadIdx.x, lane = tid & 63, w = tid >> 6;
  const int qd = lane >> 4, ml = lane & 15;

  // Q fragments straight from global (each row read by exactly one block)
  short8 aq[2];
  {
    const u16* qr = Qb + (size_t)(n0 + w * 16 + ml) * HD + qd * 8;
    aq[0] = *(const short8*)qr;
    aq[1] = *(const short8*)(qr + 32);
  }

  const int srow = tid >> 2, sjj = tid & 3;   // staging: row (key or d), 16B chunk
  const int vjj = sjj ^ (srow & 3);           // V key-chunk swizzle (bank spread)

  // prologue: tile 0 -> buf 0
#pragma unroll
  for (int s = 0; s < 2; ++s) {
    gload16(&Ks[s * 2048 + tid * 8], Kb + (size_t)srow * HD + s * 32 + sjj * 8);
    gload16(&Vs[s * 2048 + tid * 8], Vb + (size_t)srow * NS + s * 32 + vjj * 8);
  }
  __syncthreads();

  f32x4 O[4];
#pragma unroll
  for (int i = 0; i < 4; ++i) O[i] = (f32x4){0.f, 0.f, 0.f, 0.f};
  float lsum = 0.f;  // row sums for qrow=ml (this lane's column of S^T)

  const int vperm[2] = {(qd >> 1) ^ (ml & 3), (2 + (qd >> 1)) ^ (ml & 3)};
  const int vhalf = (qd & 1) * 4;

  for (int kb = 0; kb < NS / 64; ++kb) {
    const int cur = kb & 1, nxt = cur ^ 1;
    if (kb < NS / 64 - 1) {  // prefetch tile kb+1 into the other buffer
#pragma unroll
      for (int s = 0; s < 2; ++s) {
        gload16(&Ks[(nxt * 2 + s) * 2048 + tid * 8],
                Kb + (size_t)((kb + 1) * 64 + srow) * HD + s * 32 + sjj * 8);
        gload16(&Vs[(nxt * 2 + s) * 2048 + tid * 8],
                Vb + (size_t)srow * NS + (kb + 1) * 64 + s * 32 + vjj * 8);
      }
    }

    // S^T = K Q^T  (D[key][qrow]; A=K frag, B=Q frag)
    const u16* kbase = &Ks[cur * 2 * 2048];
    f32x4 S[4];
#pragma unroll
    for (int f = 0; f < 4; ++f) S[f] = (f32x4){0.f, 0.f, 0.f, 0.f};
#pragma unroll
    for (int f = 0; f < 4; ++f)
#pragma unroll
      for (int ks = 0; ks < 2; ++ks) {
        short8 bk = *(const short8*)&kbase[ks * 2048 + (f * 16 + ml) * 32 + qd * 8];
        S[f] = __builtin_amdgcn_mfma_f32_16x16x32_bf16(bk, aq[ks], S[f], 0, 0, 0);
      }

    // P = exp2(S^T) in registers; pack to 16x16x16 A-frags (zero data movement)
    s16x4 pf[4];
#pragma unroll
    for (int f = 0; f < 4; ++f) {
      float p0 = __builtin_amdgcn_exp2f(S[f][0]);
      float p1 = __builtin_amdgcn_exp2f(S[f][1]);
      float p2 = __builtin_amdgcn_exp2f(S[f][2]);
      float p3 = __builtin_amdgcn_exp2f(S[f][3]);
      lsum += (p0 + p1) + (p2 + p3);
      pf[f] = (s16x4){(short)f2bf(p0), (short)f2bf(p1),
                      (short)f2bf(p2), (short)f2bf(p3)};
    }

    // O += P V  (16 keys per step; B-frag = V[d][key] b64 reads, de-swizzled)
    const u16* vbase = &Vs[cur * 2 * 2048];
#pragma unroll
    for (int t = 0; t < 4; ++t) {
      const int vs = t >> 1;
      const int voff = vperm[t & 1] * 8 + vhalf;
#pragma unroll
      for (int df = 0; df < 4; ++df) {
        s16x4 vb = *(const s16x4*)&vbase[vs * 2048 + (df * 16 + ml) * 32 + voff];
        O[df] = MFMA_PV(pf[t], vb, O[df]);
      }
    }
    __syncthreads();  // readers of cur done + prefetch into nxt drained
  }

  // reduce lsum over the 4 quads holding the same qrow=ml
  lsum += __shfl_xor(lsum, 16);
  lsum += __shfl_xor(lsum, 32);
  float linv[4];
#pragma unroll
  for (int r = 0; r < 4; ++r) linv[r] = 1.f / __shfl(lsum, qd * 4 + r);

  const int nb = n0 + w * 16 + qd * 4;
#pragma unroll
  for (int df = 0; df < 4; ++df) {
    int d = df * 16 + ml;
    int c = d * NH + h;  // reshape: c = d*H + h
    u16x4 v;
    v.x = f2bf(O[df][0] * linv[0]); v.y = f2bf(O[df][1] * linv[1]);
    v.z = f2bf(O[df][2] * linv[2]); v.w = f2bf(O[df][3] * linv[3]);
    *(u16x4*)(XO + ((size_t)b * DM + c) * NS + nb) = v;
  }
}

extern "C" void kernel_launch(void* const* d_in, const int* in_sizes, int n_in,
                              void* d_out, int out_size, void* d_ws, size_t ws_size,
                              hipStream_t stream) {
  const float* query = (const float*)d_in[0];
  const float* key = (const float*)d_in[1];
  const float* value = (const float*)d_in[2];
  const float* Wq = (const float*)d_in[3]; const float* bq = (const float*)d_in[4];
  const float* Wk = (const float*)d_in[5]; const float* bk = (const float*)d_in[6];
  const float* Wv = (const float*)d_in[7]; const float* bv = (const float*)d_in[8];
  const float* Wm = (const float*)d_in[9]; const float* bm = (const float*)d_in[10];

  u16* ws = (u16*)d_ws;
  const size_t TS = (size_t)2 * NS * DM;   // 4,194,304 u16 elems
  const size_t WSZ = (size_t)DM * DM;
  u16* XTq = ws;
  u16* XTk = ws + TS;
  u16* XTv = ws + 2 * TS;
  u16* QH = ws + 3 * TS;
  u16* KH = ws + 4 * TS;
  u16* VH = ws + 5 * TS;
  u16* Wqb = ws + 6 * TS;
  u16* Wkb = Wqb + WSZ;
  u16* Wvb = Wkb + WSZ;
  u16* Wmb = Wvb + WSZ;
  u16* XO = XTq;   // XTq fully consumed by qkv_k before attn writes
  u16* XOT = XTk;  // XTk fully consumed before the XO transpose

  cvt4_k<<<dim3(WSZ / 1024, 4), 256, 0, stream>>>(Wq, Wk, Wv, Wm, Wqb, Wkb, Wvb, Wmb);

  dim3 tb(16, 16);
  trf3_k<<<dim3(NS / 64, DM / 64, 6), tb, 0, stream>>>(query, key, value, XTq, XTk, XTv);

  qkv_k<<<dim3(NS / 128, DM / 128, 6), 256, 0, stream>>>(
      XTq, XTk, XTv, Wqb, Wkb, Wvb, bq, bk, bv, QH, KH, VH);

  attn_k<<<dim3(NS / 64, 32), 256, 0, stream>>>(QH, KH, VH, XO);

  tr_k<<<dim3(NS / 64, DM / 64, 2), tb, 0, stream>>>(XO, XOT);
  proj_o<<<dim3(NS / 64, DM / 128, 2), 256, 0, stream>>>(XOT, Wmb, bm, (float*)d_out);
}

// Round 10
// 243.626 us; speedup vs baseline: 1.0951x; 1.0816x over previous
//
#include <hip/hip_runtime.h>
#include <stdint.h>

// MultiHeadedAttention: B=2, D_MODEL=1024, N=2048, H=16, HD=64.
// fp32 I/O, bf16 internal. Round 10: bank-conflict fix everywhere.
// LDS slabs are [rows][32 u16] (64B rows -> rows alias every 2). XOR-swizzle
// 16B chunks by s(row)=(row>>1)&3: staging picks global chunk (ci&3)^((ci>>3)&3)
// (LDS image stays wave-contiguous per the global_load_lds constraint); frag
// reads use chunk qd^((ml>>1)&3). Makes b128 frag reads conflict-free
// ({0,16,4,20,8,24,12,28} per 8-lane group) and V b64 reads 2-way (floor).
#define DM 1024
#define NS 2048
#define NH 16
#define HD 64

typedef unsigned short u16;
typedef __attribute__((ext_vector_type(8))) short short8;
typedef __attribute__((ext_vector_type(4))) short s16x4;
typedef __attribute__((ext_vector_type(8))) unsigned short u16x8;
typedef __attribute__((ext_vector_type(4))) float f32x4;
typedef __attribute__((ext_vector_type(4))) unsigned short u16x4;

// gfx90a+ legacy-shape MFMA, present on gfx950 (ISA §10: v_mfma_f32_16x16x16_bf16)
#define MFMA_PV(a, b, c) __builtin_amdgcn_mfma_f32_16x16x16bf16_1k(a, b, c, 0, 0, 0)

static __device__ __forceinline__ u16 f2bf(float f) {
  union { float f; uint32_t i; } x; x.f = f;
  return (u16)((x.i + 0x7fffu + ((x.i >> 16) & 1u)) >> 16);
}
// async global->LDS, 16B/lane; LDS side wave-uniform base + lane*16 at all sites.
static __device__ __forceinline__ void gload16(u16* lds, const u16* g) {
  auto l = (__attribute__((address_space(3))) uint32_t*)(uint32_t)(uintptr_t)lds;
  auto gp = (const __attribute__((address_space(1))) uint32_t*)(uintptr_t)g;
  __builtin_amdgcn_global_load_lds(gp, l, 16, 0, 0);
}

// -------- fused weight convert: 4x fp32[DM*DM] -> bf16 --------
__global__ __launch_bounds__(256) void cvt4_k(const float* __restrict__ a,
                                              const float* __restrict__ b,
                                              const float* __restrict__ c,
                                              const float* __restrict__ d,
                                              u16* __restrict__ oa, u16* __restrict__ ob,
                                              u16* __restrict__ oc, u16* __restrict__ od) {
  const int y = blockIdx.y;
  const float* in = y == 0 ? a : y == 1 ? b : y == 2 ? c : d;
  u16* out = y == 0 ? oa : y == 1 ? ob : y == 2 ? oc : od;
  int i = (blockIdx.x * 256 + threadIdx.x) * 4;
  f32x4 v = *(const f32x4*)(in + i);
  u16x4 o;
  o.x = f2bf(v.x); o.y = f2bf(v.y); o.z = f2bf(v.z); o.w = f2bf(v.w);
  *(u16x4*)(out + i) = o;
}

// -------- fused input transpose+downcast: fp32 [DM][NS] -> bf16 [NS][DM] -----
__global__ __launch_bounds__(256) void trf3_k(const float* __restrict__ q,
                                              const float* __restrict__ k,
                                              const float* __restrict__ v,
                                              u16* __restrict__ oq, u16* __restrict__ ok,
                                              u16* __restrict__ ov) {
  __shared__ __attribute__((aligned(16))) u16 t[64][65];
  const int z = blockIdx.z, b = z & 1, which = z >> 1;
  const float* in = which == 0 ? q : which == 1 ? k : v;
  u16* out = which == 0 ? oq : which == 1 ? ok : ov;
  const float* ip = in + (size_t)b * DM * NS;
  u16* op = out + (size_t)b * DM * NS;
  const int r0 = blockIdx.y * 64, c0 = blockIdx.x * 64;
  const int tx = threadIdx.x, ty = threadIdx.y;  // 16x16
#pragma unroll
  for (int j = 0; j < 4; ++j) {
    int row = ty + j * 16;
    f32x4 vv = *(const f32x4*)(ip + (size_t)(r0 + row) * NS + c0 + tx * 4);
    t[row][tx * 4 + 0] = f2bf(vv.x); t[row][tx * 4 + 1] = f2bf(vv.y);
    t[row][tx * 4 + 2] = f2bf(vv.z); t[row][tx * 4 + 3] = f2bf(vv.w);
  }
  __syncthreads();
#pragma unroll
  for (int j = 0; j < 4; ++j) {
    int crow = ty + j * 16;
    u16x4 vv;
    vv.x = t[tx * 4 + 0][crow]; vv.y = t[tx * 4 + 1][crow];
    vv.z = t[tx * 4 + 2][crow]; vv.w = t[tx * 4 + 3][crow];
    *(u16x4*)(op + (size_t)(c0 + crow) * DM + r0 + tx * 4) = vv;
  }
}

// -------- bf16 transpose [DM][NS] -> [NS][DM] per batch (for attn out) -------
__global__ __launch_bounds__(256) void tr_k(const u16* __restrict__ in,
                                            u16* __restrict__ out) {
  __shared__ __attribute__((aligned(16))) u16 t[64][65];
  const int b = blockIdx.z;
  const u16* ip = in + (size_t)b * DM * NS;
  u16* op = out + (size_t)b * DM * NS;
  const int r0 = blockIdx.y * 64, c0 = blockIdx.x * 64;
  const int tx = threadIdx.x, ty = threadIdx.y;
#pragma unroll
  for (int j = 0; j < 4; ++j) {
    int row = ty + j * 16;
    u16x4 v = *(const u16x4*)(ip + (size_t)(r0 + row) * NS + c0 + tx * 4);
    t[row][tx * 4 + 0] = v.x; t[row][tx * 4 + 1] = v.y;
    t[row][tx * 4 + 2] = v.z; t[row][tx * 4 + 3] = v.w;
  }
  __syncthreads();
#pragma unroll
  for (int j = 0; j < 4; ++j) {
    int crow = ty + j * 16;
    u16x4 v;
    v.x = t[tx * 4 + 0][crow]; v.y = t[tx * 4 + 1][crow];
    v.z = t[tx * 4 + 2][crow]; v.w = t[tx * 4 + 3][crow];
    *(u16x4*)(op + (size_t)(c0 + crow) * DM + r0 + tx * 4) = v;
  }
}

// ---------------- fused QKV projection GEMM ----------------
// grid (NS/128, DM/128, 6); z = which*2 + b.  128x128 tile, BK=32, swizzled LDS.
// Q output is pre-scaled by SC = 0.125*log2(e) (folded softmax scale).
__global__ __launch_bounds__(256) void qkv_k(
    const u16* __restrict__ Xq, const u16* __restrict__ Xk, const u16* __restrict__ Xv,
    const u16* __restrict__ Wq, const u16* __restrict__ Wk, const u16* __restrict__ Wv,
    const float* __restrict__ bq, const float* __restrict__ bk, const float* __restrict__ bv,
    u16* __restrict__ QH, u16* __restrict__ KH, u16* __restrict__ VH) {
  __shared__ __attribute__((aligned(16))) u16 As[128 * 32];
  __shared__ __attribute__((aligned(16))) u16 Bs[128 * 32];
  const int z = blockIdx.z, b = z & 1, which = z >> 1;
  const u16* X = which == 0 ? Xq : which == 1 ? Xk : Xv;
  const u16* W = which == 0 ? Wq : which == 1 ? Wk : Wv;
  const float* bias = which == 0 ? bq : which == 1 ? bk : bv;
  u16* out = which == 0 ? QH : which == 1 ? KH : VH;
  const float sc = which == 0 ? 0.18033688011112042f : 1.0f;  // 0.125*log2e
  const int m0 = blockIdx.x * 128;
  const int c0 = blockIdx.y * 128;
  const u16* Xb = X + (size_t)b * NS * DM;
  const int tid = threadIdx.x;
  const int lane = tid & 63, w = tid >> 6;
  const int wm = w >> 1, wc = w & 1;
  const int qd = lane >> 4, ml = lane & 15;
  const int sml = (ml >> 1) & 3;  // read-side swizzle key

  f32x4 acc[4][4];
#pragma unroll
  for (int i = 0; i < 4; ++i)
#pragma unroll
    for (int j = 0; j < 4; ++j) acc[i][j] = (f32x4){0.f, 0.f, 0.f, 0.f};

  for (int k0 = 0; k0 < DM; k0 += 32) {
    __syncthreads();
#pragma unroll
    for (int it = 0; it < 2; ++it) {
      int ci = it * 256 + tid;
      int row = ci >> 2;
      int jg = (ci & 3) ^ ((ci >> 3) & 3);  // chunk swizzle (row>>1)&3
      gload16(&As[ci * 8], Xb + (size_t)(m0 + row) * DM + k0 + jg * 8);
      gload16(&Bs[ci * 8], W + (size_t)(c0 + row) * DM + k0 + jg * 8);
    }
    __syncthreads();
    short8 af[4], bf[4];
#pragma unroll
    for (int i = 0; i < 4; ++i) {
      af[i] = *(const short8*)&As[(wm * 64 + i * 16 + ml) * 32 + ((qd ^ sml) * 8)];
      bf[i] = *(const short8*)&Bs[(wc * 64 + i * 16 + ml) * 32 + ((qd ^ sml) * 8)];
    }
#pragma unroll
    for (int mi = 0; mi < 4; ++mi)
#pragma unroll
      for (int ci2 = 0; ci2 < 4; ++ci2)
        acc[mi][ci2] = __builtin_amdgcn_mfma_f32_16x16x32_bf16(af[mi], bf[ci2],
                                                               acc[mi][ci2], 0, 0, 0);
  }

  const int cw = c0 + wc * 64;
  const int mw = m0 + wm * 64;
  float bv4[4];
#pragma unroll
  for (int ci2 = 0; ci2 < 4; ++ci2) bv4[ci2] = bias[cw + ci2 * 16 + ml];

  if (which < 2) {
    const int h = ml, d0 = cw >> 4;
    u16* ob = out + ((size_t)(b * NH + h) * NS) * HD;
#pragma unroll
    for (int mi = 0; mi < 4; ++mi) {
#pragma unroll
      for (int r = 0; r < 4; ++r) {
        int n = mw + mi * 16 + qd * 4 + r;
        u16x4 v;
        v.x = f2bf((acc[mi][0][r] + bv4[0]) * sc);
        v.y = f2bf((acc[mi][1][r] + bv4[1]) * sc);
        v.z = f2bf((acc[mi][2][r] + bv4[2]) * sc);
        v.w = f2bf((acc[mi][3][r] + bv4[3]) * sc);
        *(u16x4*)(ob + (size_t)n * HD + d0) = v;
      }
    }
  } else {
#pragma unroll
    for (int ci2 = 0; ci2 < 4; ++ci2) {
      int c = cw + ci2 * 16 + ml;
      int h = c & 15, d = c >> 4;
#pragma unroll
      for (int mi = 0; mi < 4; ++mi) {
        int nb = mw + mi * 16 + qd * 4;
        u16x4 v;
        v.x = f2bf(acc[mi][ci2][0] + bv4[ci2]); v.y = f2bf(acc[mi][ci2][1] + bv4[ci2]);
        v.z = f2bf(acc[mi][ci2][2] + bv4[ci2]); v.w = f2bf(acc[mi][ci2][3] + bv4[ci2]);
        *(u16x4*)(out + ((size_t)(b * NH + h) * HD + d) * NS + nb) = v;
      }
    }
  }
}

// ---------------- output projection, 64x128 tiles (fp32 out) ----------------
__global__ __launch_bounds__(256) void proj_o(const u16* __restrict__ X,
                                              const u16* __restrict__ W,
                                              const float* __restrict__ bias,
                                              float* __restrict__ out) {
  __shared__ __attribute__((aligned(16))) u16 As[64 * 32];
  __shared__ __attribute__((aligned(16))) u16 Bs[128 * 32];
  const int b = blockIdx.z;
  const int m0 = blockIdx.x * 64;
  const int c0 = blockIdx.y * 128;
  const u16* Xb = X + (size_t)b * NS * DM;
  const int tid = threadIdx.x;
  const int lane = tid & 63, w = tid >> 6;
  const int wm = w >> 1, wc = w & 1;  // wave tile: 32 rows x 64 cols
  const int qd = lane >> 4, ml = lane & 15;
  const int sml = (ml >> 1) & 3;

  f32x4 acc[2][4];
#pragma unroll
  for (int i = 0; i < 2; ++i)
#pragma unroll
    for (int j = 0; j < 4; ++j) acc[i][j] = (f32x4){0.f, 0.f, 0.f, 0.f};

  for (int k0 = 0; k0 < DM; k0 += 32) {
    __syncthreads();
    {  // A: 256 chunks (64 rows x 4), one per thread
      int jg = (tid & 3) ^ ((tid >> 3) & 3);
      int row = tid >> 2;
      gload16(&As[tid * 8], Xb + (size_t)(m0 + row) * DM + k0 + jg * 8);
    }
#pragma unroll
    for (int it = 0; it < 2; ++it) {  // B: 512 chunks (128 rows x 4)
      int ci = it * 256 + tid;
      int row = ci >> 2;
      int jg = (ci & 3) ^ ((ci >> 3) & 3);
      gload16(&Bs[ci * 8], W + (size_t)(c0 + row) * DM + k0 + jg * 8);
    }
    __syncthreads();
    short8 af[2], bf[4];
#pragma unroll
    for (int i = 0; i < 2; ++i)
      af[i] = *(const short8*)&As[(wm * 32 + i * 16 + ml) * 32 + ((qd ^ sml) * 8)];
#pragma unroll
    for (int i = 0; i < 4; ++i)
      bf[i] = *(const short8*)&Bs[(wc * 64 + i * 16 + ml) * 32 + ((qd ^ sml) * 8)];
#pragma unroll
    for (int mi = 0; mi < 2; ++mi)
#pragma unroll
      for (int ci2 = 0; ci2 < 4; ++ci2)
        acc[mi][ci2] = __builtin_amdgcn_mfma_f32_16x16x32_bf16(af[mi], bf[ci2],
                                                               acc[mi][ci2], 0, 0, 0);
  }

  const int cw = c0 + wc * 64;
  const int mw = m0 + wm * 32;
#pragma unroll
  for (int ci2 = 0; ci2 < 4; ++ci2) {
    int c = cw + ci2 * 16 + ml;
    float bv = bias[c];
#pragma unroll
    for (int mi = 0; mi < 2; ++mi) {
      int nb = mw + mi * 16 + qd * 4;
      f32x4 v;
      v.x = acc[mi][ci2][0] + bv; v.y = acc[mi][ci2][1] + bv;
      v.z = acc[mi][ci2][2] + bv; v.w = acc[mi][ci2][3] + bv;
      *(f32x4*)(out + ((size_t)b * DM + c) * NS + nb) = v;
    }
  }
}

// ---------------- flash attention, register-P, async dbuf, swizzled ----------
// Q,K: [bh][n][d] (Q pre-scaled by 0.125*log2e), V: [bh][d][n].
// grid (NS/64, 32). S^T = mfma(K,Q) keeps P in registers; PV via 16x16x16.
// K/V double-buffered via global_load_lds; ONE barrier per 64-key tile.
// Swizzle s(row)=(row>>1)&3 on 16B chunks: K b128 reads conflict-free, V b64
// reads 2-way (the floor for 16B placement granularity).
__global__ __launch_bounds__(256) void attn_k(const u16* __restrict__ Q,
                                              const u16* __restrict__ K,
                                              const u16* __restrict__ V,
                                              u16* __restrict__ XO) {
  __shared__ __attribute__((aligned(16))) u16 Ks[2 * 2 * 2048];  // [buf][slab][64][32]
  __shared__ __attribute__((aligned(16))) u16 Vs[2 * 2 * 2048];  // [buf][slab][64 d][32]
  const int bh = blockIdx.y, b = bh >> 4, h = bh & 15;
  const int n0 = blockIdx.x * 64;
  const u16* Qb = Q + (size_t)bh * NS * HD;
  const u16* Kb = K + (size_t)bh * NS * HD;
  const u16* Vb = V + (size_t)bh * HD * NS;
  const int tid = threadIdx.x, lane = tid & 63, w = tid >> 6;
  const int qd = lane >> 4, ml = lane & 15;
  const int sml = (ml >> 1) & 3;

  // Q fragments straight from global (each row read by exactly one block)
  short8 aq[2];
  {
    const u16* qr = Qb + (size_t)(n0 + w * 16 + ml) * HD + qd * 8;
    aq[0] = *(const short8*)qr;
    aq[1] = *(const short8*)(qr + 32);
  }

  const int srow = tid >> 2;                       // staging row (key or d)
  const int jg = (tid & 3) ^ ((tid >> 3) & 3);     // swizzled 16B chunk

  // prologue: tile 0 -> buf 0
#pragma unroll
  for (int s = 0; s < 2; ++s) {
    gload16(&Ks[s * 2048 + tid * 8], Kb + (size_t)srow * HD + s * 32 + jg * 8);
    gload16(&Vs[s * 2048 + tid * 8], Vb + (size_t)srow * NS + s * 32 + jg * 8);
  }
  __syncthreads();

  f32x4 O[4];
#pragma unroll
  for (int i = 0; i < 4; ++i) O[i] = (f32x4){0.f, 0.f, 0.f, 0.f};
  float lsum = 0.f;  // row sums for qrow=ml (this lane's column of S^T)

  for (int kb = 0; kb < NS / 64; ++kb) {
    const int cur = kb & 1, nxt = cur ^ 1;
    if (kb < NS / 64 - 1) {  // prefetch tile kb+1 into the other buffer
#pragma unroll
      for (int s = 0; s < 2; ++s) {
        gload16(&Ks[(nxt * 2 + s) * 2048 + tid * 8],
                Kb + (size_t)((kb + 1) * 64 + srow) * HD + s * 32 + jg * 8);
        gload16(&Vs[(nxt * 2 + s) * 2048 + tid * 8],
                Vb + (size_t)srow * NS + (kb + 1) * 64 + s * 32 + jg * 8);
      }
    }

    // S^T = K Q^T  (D[key][qrow]; A=K frag, B=Q frag)
    const u16* kbase = &Ks[cur * 2 * 2048];
    f32x4 S[4];
#pragma unroll
    for (int f = 0; f < 4; ++f) S[f] = (f32x4){0.f, 0.f, 0.f, 0.f};
#pragma unroll
    for (int f = 0; f < 4; ++f)
#pragma unroll
      for (int ks = 0; ks < 2; ++ks) {
        short8 bk = *(const short8*)&kbase[ks * 2048 + (f * 16 + ml) * 32 +
                                           ((qd ^ sml) * 8)];
        S[f] = __builtin_amdgcn_mfma_f32_16x16x32_bf16(bk, aq[ks], S[f], 0, 0, 0);
      }

    // P = exp2(S^T) in registers; pack to 16x16x16 A-frags (zero data movement)
    s16x4 pf[4];
#pragma unroll
    for (int f = 0; f < 4; ++f) {
      float p0 = __builtin_amdgcn_exp2f(S[f][0]);
      float p1 = __builtin_amdgcn_exp2f(S[f][1]);
      float p2 = __builtin_amdgcn_exp2f(S[f][2]);
      float p3 = __builtin_amdgcn_exp2f(S[f][3]);
      lsum += (p0 + p1) + (p2 + p3);
      pf[f] = (s16x4){(short)f2bf(p0), (short)f2bf(p1),
                      (short)f2bf(p2), (short)f2bf(p3)};
    }

    // O += P V  (16 keys per step; B-frag = V[d][key] b64 reads, de-swizzled)
    const u16* vbase = &Vs[cur * 2 * 2048];
#pragma unroll
    for (int t = 0; t < 4; ++t) {
      const int vs = t >> 1;
      const int voff = ((((t & 1) * 2 + (qd >> 1)) ^ sml) * 8) + (qd & 1) * 4;
#pragma unroll
      for (int df = 0; df < 4; ++df) {
        s16x4 vb = *(const s16x4*)&vbase[vs * 2048 + (df * 16 + ml) * 32 + voff];
        O[df] = MFMA_PV(pf[t], vb, O[df]);
      }
    }
    __syncthreads();  // readers of cur done + prefetch into nxt drained
  }

  // reduce lsum over the 4 quads holding the same qrow=ml
  lsum += __shfl_xor(lsum, 16);
  lsum += __shfl_xor(lsum, 32);
  float linv[4];
#pragma unroll
  for (int r = 0; r < 4; ++r) linv[r] = 1.f / __shfl(lsum, qd * 4 + r);

  const int nb = n0 + w * 16 + qd * 4;
#pragma unroll
  for (int df = 0; df < 4; ++df) {
    int d = df * 16 + ml;
    int c = d * NH + h;  // reshape: c = d*H + h
    u16x4 v;
    v.x = f2bf(O[df][0] * linv[0]); v.y = f2bf(O[df][1] * linv[1]);
    v.z = f2bf(O[df][2] * linv[2]); v.w = f2bf(O[df][3] * linv[3]);
    *(u16x4*)(XO + ((size_t)b * DM + c) * NS + nb) = v;
  }
}

extern "C" void kernel_launch(void* const* d_in, const int* in_sizes, int n_in,
                              void* d_out, int out_size, void* d_ws, size_t ws_size,
                              hipStream_t stream) {
  const float* query = (const float*)d_in[0];
  const float* key = (const float*)d_in[1];
  const float* value = (const float*)d_in[2];
  const float* Wq = (const float*)d_in[3]; const float* bq = (const float*)d_in[4];
  const float* Wk = (const float*)d_in[5]; const float* bk = (const float*)d_in[6];
  const float* Wv = (const float*)d_in[7]; const float* bv = (const float*)d_in[8];
  const float* Wm = (const float*)d_in[9]; const float* bm = (const float*)d_in[10];

  u16* ws = (u16*)d_ws;
  const size_t TS = (size_t)2 * NS * DM;   // 4,194,304 u16 elems
  const size_t WSZ = (size_t)DM * DM;
  u16* XTq = ws;
  u16* XTk = ws + TS;
  u16* XTv = ws + 2 * TS;
  u16* QH = ws + 3 * TS;
  u16* KH = ws + 4 * TS;
  u16* VH = ws + 5 * TS;
  u16* Wqb = ws + 6 * TS;
  u16* Wkb = Wqb + WSZ;
  u16* Wvb = Wkb + WSZ;
  u16* Wmb = Wvb + WSZ;
  u16* XO = XTq;   // XTq fully consumed by qkv_k before attn writes
  u16* XOT = XTk;  // XTk fully consumed before the XO transpose

  cvt4_k<<<dim3(WSZ / 1024, 4), 256, 0, stream>>>(Wq, Wk, Wv, Wm, Wqb, Wkb, Wvb, Wmb);

  dim3 tb(16, 16);
  trf3_k<<<dim3(NS / 64, DM / 64, 6), tb, 0, stream>>>(query, key, value, XTq, XTk, XTv);

  qkv_k<<<dim3(NS / 128, DM / 128, 6), 256, 0, stream>>>(
      XTq, XTk, XTv, Wqb, Wkb, Wvb, bq, bk, bv, QH, KH, VH);

  attn_k<<<dim3(NS / 64, 32), 256, 0, stream>>>(QH, KH, VH, XO);

  tr_k<<<dim3(NS / 64, DM / 64, 2), tb, 0, stream>>>(XO, XOT);
  proj_o<<<dim3(NS / 64, DM / 128, 2), 256, 0, stream>>>(XOT, Wmb, bm, (float*)d_out);
}